// Round 4
// baseline (284.251 us; speedup 1.0000x reference)
//
#include <hip/hip_runtime.h>

#define S_LEN 2048
#define HDIM  512
#define KSZ   64
#define HALFK 32
#define S_T   128     // seq rows per block
#define PH    16      // rows per phase
// 1/sqrt(2048)
#define INV_SQRT_S 0.02209708691207961f

struct Smem {
    float  pbuf[2][PH][HDIM];   // 64 KB: per-half conv partials
    float  hbuf[PH][HDIM];      // 32 KB: combined h-values
    float2 part[PH][64];        // 8 KB: stage-1 partial (sum, sumsq)
    float2 stats[PH];           // (mean, rstd) per row
};

__device__ __forceinline__ void lds_barrier() {
    // LDS-only barrier: drain lgkmcnt but leave global loads/stores (vmcnt) in flight.
    asm volatile("s_waitcnt lgkmcnt(0)\n\ts_barrier" ::: "memory");
}

// One 16-row conv phase for this thread's 32 taps. OFF in {0,16} keeps every
// ring index compile-time static. mbase = first row index (already shifted by
// -32 for half 1). Writes p = res*x + INV*partial_y into pdst[j2*HDIM] where
// pdst = &pbuf[half][0][h]  (h already folded into pdst — DO NOT add h again).
template <int OFF>
__device__ __forceinline__ void conv_phase(const float* __restrict__ xb, int mbase, int h, float res,
                                           const float (&wr)[HALFK], float (&xw)[HALFK],
                                           float (&xp)[4], float* __restrict__ pdst)
{
#pragma unroll
    for (int j2 = 0; j2 < PH; ++j2) {
        const float xcur = xp[j2 & 3];
        // re-issue this prefetch slot for row mbase + j2 + 4 (wrap harmless)
        xp[j2 & 3] = xb[((mbase + j2 + 4) & (S_LEN - 1)) * HDIM + h];

        xw[(OFF + j2) & 31] = xcur;   // insert current row
        float y0 = 0.f, y1 = 0.f, y2 = 0.f, y3 = 0.f;
#pragma unroll
        for (int i = 0; i < HALFK; i += 4) {
            y0 = fmaf(wr[i],     xw[(OFF + j2 - i)     & 31], y0);
            y1 = fmaf(wr[i + 1], xw[(OFF + j2 - i - 1) & 31], y1);
            y2 = fmaf(wr[i + 2], xw[(OFF + j2 - i - 2) & 31], y2);
            y3 = fmaf(wr[i + 3], xw[(OFF + j2 - i - 3) & 31], y3);
        }
        const float y = (y0 + y1) + (y2 + y3);
        pdst[j2 * HDIM] = fmaf(res, xcur, INV_SQRT_S * y);
    }
}

__device__ __forceinline__ void ln_phase(int srow0, int tid, int h, float gm, float bt,
                                         float* __restrict__ ob, Smem* sm)
{
    lds_barrier();   // all pbuf writes visible

    // Stage 1: 64 threads per row; combine halves, stash hval, accumulate moments
    const int r = tid >> 6, c = tid & 63;
    float s1 = 0.f, q1 = 0.f;
#pragma unroll
    for (int m = 0; m < 8; ++m) {
        const int col = c + (m << 6);
        const float v = sm->pbuf[0][r][col] + sm->pbuf[1][r][col];
        sm->hbuf[r][col] = v;
        s1 += v;
        q1 = fmaf(v, v, q1);
    }
    sm->part[r][c] = make_float2(s1, q1);
    lds_barrier();

    // Stage 2: 16 lanes per row, shuffle-combine within 16-lane groups
    if (tid < 256) {
        const int rr = tid >> 4, q = tid & 15;
        float ts = 0.f, tq = 0.f;
#pragma unroll
        for (int i = 0; i < 4; ++i) {
            const float2 p = sm->part[rr][q * 4 + i];
            ts += p.x; tq += p.y;
        }
        ts += __shfl_xor(ts, 1, 64); tq += __shfl_xor(tq, 1, 64);
        ts += __shfl_xor(ts, 2, 64); tq += __shfl_xor(tq, 2, 64);
        ts += __shfl_xor(ts, 4, 64); tq += __shfl_xor(tq, 4, 64);
        ts += __shfl_xor(ts, 8, 64); tq += __shfl_xor(tq, 8, 64);
        if (q == 0) {
            const float mean = ts * (1.0f / 512.0f);
            const float var  = fmaf(tq, 1.0f / 512.0f, -mean * mean);
            sm->stats[rr] = make_float2(mean, rsqrtf(var + 1e-12f));
        }
    }
    lds_barrier();

    // Epilogue: 1024 threads, 8 rows each; broadcast stats; coalesced stores
    const int half = tid >> 9;
#pragma unroll
    for (int i = 0; i < 8; ++i) {
        const int rr = half * 8 + i;
        const float2 st = sm->stats[rr];
        const float v = sm->hbuf[rr][h];
        ob[(srow0 + rr) * HDIM + h] = fmaf((v - st.x) * st.y, gm, bt);
    }
}

__global__ __launch_bounds__(1024, 4)
void fconv_ln(const float* __restrict__ x, const float* __restrict__ w,
              const float* __restrict__ gamma, const float* __restrict__ beta,
              float* __restrict__ out)
{
    __shared__ Smem sm;
    const int tid    = threadIdx.x;
    const int h      = tid & (HDIM - 1);
    const int half   = tid >> 9;           // wave-uniform (waves 0-7 vs 8-15)
    const int halfsh = half << 5;          // tap offset 0 or 32
    const int b      = blockIdx.x >> 4;    // 16 tiles of 128 rows per batch
    const int s0     = (blockIdx.x & 15) * S_T;

    const float* xb = x   + (size_t)b * S_LEN * HDIM;
    float*       ob = out + (size_t)b * S_LEN * HDIM;

    float wr[HALFK];
#pragma unroll
    for (int i = 0; i < HALFK; ++i) wr[i] = w[(halfsh + i) * HDIM + h];
    const float gm  = gamma[h], bt = beta[h];
    const float res = half ? 0.0f : 1.0f;  // residual only from half 0

    // this half's row cursor: local row j maps to global row m0 + j
    const int m0 = s0 - halfsh;

    // window init: slot (32-d)&31 holds x[m0-d], d = 1..31
    float xw[HALFK];
#pragma unroll
    for (int d = 1; d < HALFK; ++d)
        xw[(HALFK - d) & 31] = xb[((m0 - d) & (S_LEN - 1)) * HDIM + h];
    xw[0] = 0.f;

    // prefetch pipeline: rows m0 .. m0+3
    float xp[4];
#pragma unroll
    for (int j = 0; j < 4; ++j)
        xp[j] = xb[((m0 + j) & (S_LEN - 1)) * HDIM + h];

    float* pdst = &sm.pbuf[half][0][h];    // h folded in ONCE

#pragma unroll 1
    for (int g = 0; g < S_T / (2 * PH); ++g) {   // 4 iterations, 2 phases each
        const int jb = g * 2 * PH;
        conv_phase<0> (xb, m0 + jb,      h, res, wr, xw, xp, pdst);
        ln_phase(s0 + jb,      tid, h, gm, bt, ob, &sm);
        conv_phase<16>(xb, m0 + jb + PH, h, res, wr, xw, xp, pdst);
        ln_phase(s0 + jb + PH, tid, h, gm, bt, ob, &sm);
    }
}

extern "C" void kernel_launch(void* const* d_in, const int* in_sizes, int n_in,
                              void* d_out, int out_size, void* d_ws, size_t ws_size,
                              hipStream_t stream) {
    const float* x  = (const float*)d_in[0];   // [32, 2048, 512] fp32
    const float* w  = (const float*)d_in[1];   // [1, 64, 512]   fp32
    const float* g  = (const float*)d_in[2];   // [512]
    const float* b  = (const float*)d_in[3];   // [512]
    float* o        = (float*)d_out;           // [32, 2048, 512] fp32

    (void)in_sizes; (void)n_in; (void)out_size; (void)d_ws; (void)ws_size;
    fconv_ln<<<dim3(32 * (S_LEN / S_T)), dim3(1024), 0, stream>>>(x, w, g, b, o);
}